// Round 1
// baseline (133.942 us; speedup 1.0000x reference)
//
#include <hip/hip_runtime.h>

#define N_NODES 8192
#define NODE_IN 128
#define OUT_DIM 128
#define EDGE_IN 64
#define N_EDGES 262144
#define MAXK 1024

// ---------------- K1: h = x @ W^T  (h[i][c] = sum_k x[i][k] * W[c][k]) ----------------
__global__ __launch_bounds__(128) void k_gemm(const float* __restrict__ x,
                                              const float* __restrict__ W,
                                              float* __restrict__ h) {
    __shared__ float xs[8][128];
    const int col = threadIdx.x;
    const int r0 = blockIdx.x * 8;
    #pragma unroll
    for (int r = 0; r < 8; ++r) xs[r][col] = x[(r0 + r) * 128 + col];
    __syncthreads();
    float acc[8] = {0.f, 0.f, 0.f, 0.f, 0.f, 0.f, 0.f, 0.f};
    #pragma unroll 4
    for (int k0 = 0; k0 < 128; k0 += 4) {
        const float4 wv = *reinterpret_cast<const float4*>(&W[col * 128 + k0]);
        #pragma unroll
        for (int r = 0; r < 8; ++r) {
            const float4 xv = *reinterpret_cast<const float4*>(&xs[r][k0]);
            acc[r] += xv.x * wv.x + xv.y * wv.y + xv.z * wv.z + xv.w * wv.w;
        }
    }
    #pragma unroll
    for (int r = 0; r < 8; ++r) h[(r0 + r) * 128 + col] = acc[r];
}

// ---------------- K2: alpha_src[n] = h[n].a[0:128], alpha_dst[n] = h[n].a[128:256] ----
__global__ __launch_bounds__(256) void k_alpha(const float* __restrict__ h,
                                               const float* __restrict__ a,
                                               float* __restrict__ asrc,
                                               float* __restrict__ adst) {
    const int n = blockIdx.x * 256 + threadIdx.x;
    float s1 = 0.f, s2 = 0.f;
    #pragma unroll 8
    for (int k = 0; k < 128; k += 4) {
        const float4 hv = *reinterpret_cast<const float4*>(&h[n * 128 + k]);
        const float4 a1 = *reinterpret_cast<const float4*>(&a[k]);
        const float4 a2 = *reinterpret_cast<const float4*>(&a[128 + k]);
        s1 += hv.x * a1.x + hv.y * a1.y + hv.z * a1.z + hv.w * a1.w;
        s2 += hv.x * a2.x + hv.y * a2.y + hv.z * a2.z + hv.w * a2.w;
    }
    asrc[n] = s1;
    adst[n] = s2;
}

// ---------------- K3: S[c] = sum_rows h[r][c]  (deterministic tree reduce) -----------
__global__ __launch_bounds__(256) void k_colsum(const float* __restrict__ h,
                                                float* __restrict__ S) {
    __shared__ float red[256];
    const int c = blockIdx.x;
    float s = 0.f;
    for (int r = threadIdx.x; r < N_NODES; r += 256) s += h[r * 128 + c];
    red[threadIdx.x] = s;
    __syncthreads();
    for (int o = 128; o > 0; o >>= 1) {
        if (threadIdx.x < o) red[threadIdx.x] += red[threadIdx.x + o];
        __syncthreads();
    }
    if (threadIdx.x == 0) S[c] = red[0];
}

// ---------------- K4: per-edge e = leakyrelu(asrc[s]+adst[t]+ea.a3), histogram -------
__global__ __launch_bounds__(256) void k_edge(const int* __restrict__ ei,
                                              const float* __restrict__ ea,
                                              const float* __restrict__ a,
                                              const float* __restrict__ asrc,
                                              const float* __restrict__ adst,
                                              float* __restrict__ e,
                                              int* __restrict__ counts) {
    const int lane16 = threadIdx.x & 15;
    const int g = threadIdx.x >> 4;
    const int eid = blockIdx.x * 16 + g;
    const float4 av = *reinterpret_cast<const float4*>(&a[256 + lane16 * 4]);
    const float4 ev = *reinterpret_cast<const float4*>(&ea[(size_t)eid * 64 + lane16 * 4]);
    float d = ev.x * av.x + ev.y * av.y + ev.z * av.z + ev.w * av.w;
    d += __shfl_xor(d, 1);
    d += __shfl_xor(d, 2);
    d += __shfl_xor(d, 4);
    d += __shfl_xor(d, 8);
    if (lane16 == 0) {
        const int s = ei[eid];
        const int t = ei[N_EDGES + eid];
        const float v = asrc[s] + adst[t] + d;
        e[eid] = v > 0.f ? v : 0.2f * v;
        atomicAdd(&counts[s], 1);
    }
}

// ---------------- K5: exclusive scan of counts -> offsets, cursor --------------------
__global__ __launch_bounds__(1024) void k_scan(const int* __restrict__ counts,
                                               int* __restrict__ offsets,
                                               int* __restrict__ cursor) {
    __shared__ int lds[1024];
    const int t = threadIdx.x;
    int v[8];
    int s = 0;
    #pragma unroll
    for (int i = 0; i < 8; ++i) { v[i] = counts[t * 8 + i]; s += v[i]; }
    lds[t] = s;
    __syncthreads();
    for (int off = 1; off < 1024; off <<= 1) {
        const int add = (t >= off) ? lds[t - off] : 0;
        __syncthreads();
        lds[t] += add;
        __syncthreads();
    }
    int ex = lds[t] - s;  // exclusive prefix
    #pragma unroll
    for (int i = 0; i < 8; ++i) {
        offsets[t * 8 + i] = ex;
        cursor[t * 8 + i] = ex;
        ex += v[i];
    }
}

// ---------------- K6: scatter edge ids into per-row buckets --------------------------
__global__ __launch_bounds__(256) void k_scatter(const int* __restrict__ ei,
                                                 int* __restrict__ cursor,
                                                 int* __restrict__ bucket) {
    const int eid = blockIdx.x * 256 + threadIdx.x;
    const int s = ei[eid];
    const int pos = atomicAdd(&cursor[s], 1);
    bucket[pos] = eid;
}

// ---------------- K7: per-row dedup (last-edge-wins) + softmax + aggregate -----------
__global__ __launch_bounds__(128) void k_row(const int* __restrict__ ei,
                                             const float* __restrict__ e,
                                             const int* __restrict__ offsets,
                                             const int* __restrict__ counts,
                                             const int* __restrict__ bucket,
                                             const float* __restrict__ h,
                                             const float* __restrict__ S,
                                             float* __restrict__ out) {
    __shared__ int dst_l[MAXK];
    __shared__ int eid_l[MAXK];
    __shared__ float e_l[MAXK];
    __shared__ float cw[MAXK];
    __shared__ int cd[MAXK];
    __shared__ float red[128];
    __shared__ int nw_s;

    const int row = blockIdx.x;
    const int tid = threadIdx.x;
    int k = counts[row];
    if (k > MAXK) k = MAXK;  // statistically impossible (Poisson mean 32)
    const int off = offsets[row];
    for (int t = tid; t < k; t += 128) {
        const int id = bucket[off + t];
        eid_l[t] = id;
        dst_l[t] = ei[N_EDGES + id];
        e_l[t] = e[id];
    }
    if (tid == 0) nw_s = 0;
    __syncthreads();

    // winners: last-write-wins per (src,dst) cell == max edge id among same dst
    float mloc = 0.0f;  // zeros of non-edge cells always present -> m >= 0
    for (int t = tid; t < k; t += 128) {
        const int d = dst_l[t];
        const int id = eid_l[t];
        bool win = true;
        for (int s2 = 0; s2 < k; ++s2) {
            if (dst_l[s2] == d && eid_l[s2] > id) { win = false; break; }
        }
        if (win) {
            const float ev = e_l[t];
            mloc = fmaxf(mloc, ev);
            const int p = atomicAdd(&nw_s, 1);
            cd[p] = d;
            cw[p] = ev;  // store e temporarily
        }
    }
    red[tid] = mloc;
    __syncthreads();
    for (int o = 64; o > 0; o >>= 1) {
        if (tid < o) red[tid] = fmaxf(red[tid], red[tid + o]);
        __syncthreads();
    }
    const float m = red[0];
    const int nw = nw_s;
    __syncthreads();

    const float w0 = expf(-m);
    float sloc = 0.f;
    for (int j = tid; j < nw; j += 128) {
        const float w = expf(cw[j] - m);
        sloc += w;
        cw[j] = w - w0;
    }
    red[tid] = sloc;
    __syncthreads();
    for (int o = 64; o > 0; o >>= 1) {
        if (tid < o) red[tid] += red[tid + o];
        __syncthreads();
    }
    const float D = (float)(N_NODES - nw) * w0 + red[0];
    __syncthreads();

    // aggregate over winner cells + uniform background term
    float acc = w0 * S[tid];
    for (int j = 0; j < nw; ++j) {
        acc += cw[j] * h[cd[j] * 128 + tid];
    }
    out[row * 128 + tid] = acc / D;
}

extern "C" void kernel_launch(void* const* d_in, const int* in_sizes, int n_in,
                              void* d_out, int out_size, void* d_ws, size_t ws_size,
                              hipStream_t stream) {
    const float* x = (const float*)d_in[0];
    const int* ei = (const int*)d_in[1];
    const float* ea = (const float*)d_in[2];
    const float* W = (const float*)d_in[3];
    const float* a = (const float*)d_in[4];
    float* out = (float*)d_out;

    char* ws = (char*)d_ws;
    float* h = (float*)(ws + 0);                  // 4 MB
    float* e = (float*)(ws + 4194304);            // 1 MB
    int* bucket = (int*)(ws + 5242880);           // 1 MB
    float* asrc = (float*)(ws + 6291456);         // 32 KB
    float* adst = (float*)(ws + 6324224);         // 32 KB
    int* counts = (int*)(ws + 6356992);           // 32 KB
    int* offsets = (int*)(ws + 6389760);          // 32 KB
    int* cursor = (int*)(ws + 6422528);           // 32 KB
    float* S = (float*)(ws + 6455296);            // 512 B

    hipMemsetAsync(counts, 0, N_NODES * sizeof(int), stream);

    k_gemm<<<N_NODES / 8, 128, 0, stream>>>(x, W, h);
    k_alpha<<<N_NODES / 256, 256, 0, stream>>>(h, a, asrc, adst);
    k_colsum<<<128, 256, 0, stream>>>(h, S);
    k_edge<<<N_EDGES / 16, 256, 0, stream>>>(ei, ea, a, asrc, adst, e, counts);
    k_scan<<<1, 1024, 0, stream>>>(counts, offsets, cursor);
    k_scatter<<<N_EDGES / 256, 256, 0, stream>>>(ei, cursor, bucket);
    k_row<<<N_NODES, 128, 0, stream>>>(ei, e, offsets, counts, bucket, h, S, out);
}

// Round 2
// 99.935 us; speedup vs baseline: 1.3403x; 1.3403x over previous
//
#include <hip/hip_runtime.h>

#define N_NODES 8192
#define N_EDGES 262144
#define CAP 128

// ---- K1: h = x@W^T, fused: asrc/adst dots vs a[0:128]/a[128:256], colsum S ----
__global__ __launch_bounds__(128) void k_gemm(const float* __restrict__ x,
                                              const float* __restrict__ W,
                                              const float* __restrict__ a,
                                              float* __restrict__ h,
                                              float* __restrict__ asrc,
                                              float* __restrict__ adst,
                                              float* __restrict__ S) {
    __shared__ float xs[8][128];
    __shared__ float ps[2][8], pd[2][8];
    const int col = threadIdx.x;
    const int r0 = blockIdx.x * 8;
    #pragma unroll
    for (int r = 0; r < 8; ++r) xs[r][col] = x[(r0 + r) * 128 + col];
    __syncthreads();
    float acc[8] = {0.f,0.f,0.f,0.f,0.f,0.f,0.f,0.f};
    #pragma unroll 4
    for (int k0 = 0; k0 < 128; k0 += 4) {
        const float4 wv = *reinterpret_cast<const float4*>(&W[col * 128 + k0]);
        #pragma unroll
        for (int r = 0; r < 8; ++r) {
            const float4 xv = *reinterpret_cast<const float4*>(&xs[r][k0]);
            acc[r] += xv.x*wv.x + xv.y*wv.y + xv.z*wv.z + xv.w*wv.w;
        }
    }
    float csum = 0.f;
    #pragma unroll
    for (int r = 0; r < 8; ++r) { h[(r0 + r) * 128 + col] = acc[r]; csum += acc[r]; }
    atomicAdd(&S[col], csum);
    const float a1 = a[col], a2 = a[128 + col];
    const int wid = col >> 6;
    #pragma unroll
    for (int r = 0; r < 8; ++r) {
        float v1 = acc[r] * a1, v2 = acc[r] * a2;
        #pragma unroll
        for (int o = 32; o > 0; o >>= 1) { v1 += __shfl_down(v1, o); v2 += __shfl_down(v2, o); }
        if ((col & 63) == 0) { ps[wid][r] = v1; pd[wid][r] = v2; }
    }
    __syncthreads();
    if (col < 8)       asrc[r0 + col]     = ps[0][col]     + ps[1][col];
    else if (col < 16) adst[r0 + col - 8] = pd[0][col - 8] + pd[1][col - 8];
}

// ---- K2: per-edge e = leakyrelu(asrc[s]+adst[t]+ea.a3); direct bucket scatter ----
__global__ __launch_bounds__(256) void k_edge(const int* __restrict__ ei,
                                              const float* __restrict__ ea,
                                              const float* __restrict__ a,
                                              const float* __restrict__ asrc,
                                              const float* __restrict__ adst,
                                              float* __restrict__ e,
                                              int* __restrict__ counts,
                                              int* __restrict__ bucket) {
    const int lane16 = threadIdx.x & 15;
    const int eid = blockIdx.x * 16 + (threadIdx.x >> 4);
    const float4 av = *reinterpret_cast<const float4*>(&a[256 + lane16 * 4]);
    const float4 ev = *reinterpret_cast<const float4*>(&ea[(size_t)eid * 64 + lane16 * 4]);
    float d = ev.x*av.x + ev.y*av.y + ev.z*av.z + ev.w*av.w;
    d += __shfl_xor(d, 1);
    d += __shfl_xor(d, 2);
    d += __shfl_xor(d, 4);
    d += __shfl_xor(d, 8);
    if (lane16 == 0) {
        const int s = ei[eid];
        const int t = ei[N_EDGES + eid];
        const float v = asrc[s] + adst[t] + d;
        e[eid] = v > 0.f ? v : 0.2f * v;
        const int pos = atomicAdd(&counts[s], 1);
        if (pos < CAP) bucket[s * CAP + pos] = eid;
    }
}

// ---- K3: per-row dedup (last-edge-wins) + sparse softmax + aggregate ----
// attention row = nw winner cells (value e) + (N-nw) zero cells.
// out_i = (w0*S + sum (exp(e-m)-w0)*h_dst) / D,  D=(N-nw)*w0 + sum exp(e-m)
__global__ __launch_bounds__(128) void k_row(const int* __restrict__ ei,
                                             const float* __restrict__ e,
                                             const int* __restrict__ counts,
                                             const int* __restrict__ bucket,
                                             const float* __restrict__ h,
                                             const float* __restrict__ S,
                                             float* __restrict__ out) {
    __shared__ int dst_l[CAP];
    __shared__ int eid_l[CAP];
    __shared__ float e_l[CAP];
    __shared__ float cw[CAP];
    __shared__ int cd[CAP];
    __shared__ float redm[2], reds[2];
    __shared__ int nw_s;

    const int row = blockIdx.x;
    const int tid = threadIdx.x;
    int k = counts[row];
    if (k > CAP) k = CAP;  // statistically impossible (max count ~60)
    const float Sv = S[tid];
    if (tid < k) {
        const int id = bucket[row * CAP + tid];
        eid_l[tid] = id;
        dst_l[tid] = ei[N_EDGES + id];
        e_l[tid] = e[id];
    }
    if (tid == 0) nw_s = 0;
    __syncthreads();

    // winner per (row,dst) cell = max edge id (last-write-wins scatter semantics)
    float mloc = 0.f;  // non-edge zeros always present -> m >= 0
    if (tid < k) {
        const int d = dst_l[tid];
        const int id = eid_l[tid];
        bool win = true;
        for (int s2 = 0; s2 < k; ++s2)
            if (dst_l[s2] == d && eid_l[s2] > id) { win = false; break; }
        if (win) {
            const float ev = e_l[tid];
            mloc = ev > 0.f ? ev : 0.f;
            const int p = atomicAdd(&nw_s, 1);
            cd[p] = d;
            cw[p] = ev;
        }
    }
    #pragma unroll
    for (int o = 32; o > 0; o >>= 1) mloc = fmaxf(mloc, __shfl_down(mloc, o));
    if ((tid & 63) == 0) redm[tid >> 6] = mloc;
    __syncthreads();
    const float m = fmaxf(redm[0], redm[1]);
    const int nw = nw_s;
    const float w0 = expf(-m);
    float sloc = 0.f;
    if (tid < nw) {
        const float w = expf(cw[tid] - m);
        sloc = w;
        cw[tid] = w - w0;
    }
    #pragma unroll
    for (int o = 32; o > 0; o >>= 1) sloc += __shfl_down(sloc, o);
    if ((tid & 63) == 0) reds[tid >> 6] = sloc;
    __syncthreads();  // also publishes cw updates
    const float D = (float)(N_NODES - nw) * w0 + reds[0] + reds[1];

    float acc = w0 * Sv;
    int j = 0;
    for (; j + 3 < nw; j += 4) {
        const float c0 = cw[j], c1 = cw[j+1], c2 = cw[j+2], c3 = cw[j+3];
        const int d0 = cd[j], d1 = cd[j+1], d2 = cd[j+2], d3 = cd[j+3];
        acc += c0 * h[d0 * 128 + tid] + c1 * h[d1 * 128 + tid]
             + c2 * h[d2 * 128 + tid] + c3 * h[d3 * 128 + tid];
    }
    for (; j < nw; ++j) acc += cw[j] * h[cd[j] * 128 + tid];
    out[row * 128 + tid] = acc / D;
}

extern "C" void kernel_launch(void* const* d_in, const int* in_sizes, int n_in,
                              void* d_out, int out_size, void* d_ws, size_t ws_size,
                              hipStream_t stream) {
    const float* x = (const float*)d_in[0];
    const int* ei = (const int*)d_in[1];
    const float* ea = (const float*)d_in[2];
    const float* W = (const float*)d_in[3];
    const float* a = (const float*)d_in[4];
    float* out = (float*)d_out;

    char* ws = (char*)d_ws;
    float* h = (float*)(ws);                          // 4 MB
    int* bucket = (int*)(ws + (4 << 20));             // 4 MB
    float* e = (float*)(ws + (8 << 20));              // 1 MB
    float* asrc = (float*)(ws + (9 << 20));           // 32 KB
    float* adst = (float*)(ws + (9 << 20) + 32768);   // 32 KB
    int* counts = (int*)(ws + (9 << 20) + 65536);     // 32 KB
    float* S = (float*)(ws + (9 << 20) + 98304);      // 512 B (adjacent to counts)

    hipMemsetAsync(counts, 0, N_NODES * sizeof(int) + 128 * sizeof(float), stream);

    k_gemm<<<N_NODES / 8, 128, 0, stream>>>(x, W, a, h, asrc, adst, S);
    k_edge<<<N_EDGES / 16, 256, 0, stream>>>(ei, ea, a, asrc, adst, e, counts, bucket);
    k_row<<<N_NODES, 128, 0, stream>>>(ei, e, counts, bucket, h, S, out);
}

// Round 3
// 98.652 us; speedup vs baseline: 1.3577x; 1.0130x over previous
//
#include <hip/hip_runtime.h>

#define N_NODES 8192
#define N_EDGES 262144
#define CAP 128

// ---- K1: h = x@W^T with W staged in LDS (padded stride 132 -> conflict-free b128).
//      Fused epilogue: asrc/adst dots vs a[0:128]/a[128:256], colsum S (atomic).
//      Block 256 = (col 0..127) x (row-half 0..1); 16 rows/block; grid 512.
__global__ __launch_bounds__(256) void k_gemm(const float* __restrict__ x,
                                              const float* __restrict__ W,
                                              const float* __restrict__ a,
                                              float* __restrict__ h,
                                              float* __restrict__ asrc,
                                              float* __restrict__ adst,
                                              float* __restrict__ S) {
    __shared__ float wlds[128 * 132];   // 67584 B, stride 132: bank-quad (c + k/4)%8
    __shared__ float xlds[16 * 128];    // 8192 B
    __shared__ float ps[4][8], pd[4][8];

    const int tid = threadIdx.x;
    const int c = tid & 127;
    const int rh = tid >> 7;
    const int r0 = blockIdx.x * 16;

    // stage x rows r0..r0+15 (512 float4s)
    #pragma unroll
    for (int i = tid; i < 512; i += 256) {
        const int row = i >> 5, k4 = i & 31;
        *reinterpret_cast<float4*>(&xlds[row * 128 + k4 * 4]) =
            *reinterpret_cast<const float4*>(&x[(size_t)(r0 + row) * 128 + k4 * 4]);
    }
    // stage W (4096 float4s)
    #pragma unroll
    for (int i = tid; i < 4096; i += 256) {
        const int wr = i >> 5, k4 = i & 31;
        *reinterpret_cast<float4*>(&wlds[wr * 132 + k4 * 4]) =
            *reinterpret_cast<const float4*>(&W[(size_t)wr * 128 + k4 * 4]);
    }
    __syncthreads();

    float acc[8] = {0.f,0.f,0.f,0.f,0.f,0.f,0.f,0.f};
    #pragma unroll 8
    for (int k0 = 0; k0 < 128; k0 += 4) {
        const float4 wv = *reinterpret_cast<const float4*>(&wlds[c * 132 + k0]);
        #pragma unroll
        for (int r = 0; r < 8; ++r) {
            const float4 xv = *reinterpret_cast<const float4*>(&xlds[(rh * 8 + r) * 128 + k0]);
            acc[r] += xv.x*wv.x + xv.y*wv.y + xv.z*wv.z + xv.w*wv.w;
        }
    }

    float csum = 0.f;
    #pragma unroll
    for (int r = 0; r < 8; ++r) {
        h[(size_t)(r0 + rh * 8 + r) * 128 + c] = acc[r];
        csum += acc[r];
    }
    atomicAdd(&S[c], csum);

    const float a1 = a[c], a2 = a[128 + c];
    const int wid = tid >> 6;
    #pragma unroll
    for (int r = 0; r < 8; ++r) {
        float v1 = acc[r] * a1, v2 = acc[r] * a2;
        #pragma unroll
        for (int o = 32; o > 0; o >>= 1) { v1 += __shfl_down(v1, o); v2 += __shfl_down(v2, o); }
        if ((tid & 63) == 0) { ps[wid][r] = v1; pd[wid][r] = v2; }
    }
    __syncthreads();
    // rows r0 + H*8 + r: contributed by waves 2H and 2H+1
    if (tid < 16) {
        const int H = tid >> 3, r = tid & 7;
        asrc[r0 + H * 8 + r] = ps[2 * H][r] + ps[2 * H + 1][r];
    } else if (tid < 32) {
        const int t = tid - 16, H = t >> 3, r = t & 7;
        adst[r0 + H * 8 + r] = pd[2 * H][r] + pd[2 * H + 1][r];
    }
}

// ---- K2: per-edge e = leakyrelu(asrc[s]+adst[t]+ea.a3); direct bucket scatter ----
__global__ __launch_bounds__(256) void k_edge(const int* __restrict__ ei,
                                              const float* __restrict__ ea,
                                              const float* __restrict__ a,
                                              const float* __restrict__ asrc,
                                              const float* __restrict__ adst,
                                              float* __restrict__ e,
                                              int* __restrict__ counts,
                                              int* __restrict__ bucket) {
    const int lane16 = threadIdx.x & 15;
    const int eid = blockIdx.x * 16 + (threadIdx.x >> 4);
    const float4 av = *reinterpret_cast<const float4*>(&a[256 + lane16 * 4]);
    const float4 ev = *reinterpret_cast<const float4*>(&ea[(size_t)eid * 64 + lane16 * 4]);
    float d = ev.x*av.x + ev.y*av.y + ev.z*av.z + ev.w*av.w;
    d += __shfl_xor(d, 1);
    d += __shfl_xor(d, 2);
    d += __shfl_xor(d, 4);
    d += __shfl_xor(d, 8);
    if (lane16 == 0) {
        const int s = ei[eid];
        const int t = ei[N_EDGES + eid];
        const float v = asrc[s] + adst[t] + d;
        e[eid] = v > 0.f ? v : 0.2f * v;
        const int pos = atomicAdd(&counts[s], 1);
        if (pos < CAP) bucket[s * CAP + pos] = eid;
    }
}

// ---- K3: per-row dedup (last-edge-wins) + sparse softmax + aggregate ----
// out_i = (w0*S + sum (exp(e-m)-w0)*h_dst) / D,  D=(N-nw)*w0 + sum exp(e-m)
__global__ __launch_bounds__(128) void k_row(const int* __restrict__ ei,
                                             const float* __restrict__ e,
                                             const int* __restrict__ counts,
                                             const int* __restrict__ bucket,
                                             const float* __restrict__ h,
                                             const float* __restrict__ S,
                                             float* __restrict__ out) {
    __shared__ int dst_l[CAP];
    __shared__ int eid_l[CAP];
    __shared__ float e_l[CAP];
    __shared__ float cw[CAP];
    __shared__ int cd[CAP];
    __shared__ float redm[2], reds[2];
    __shared__ int nw_s;

    const int row = blockIdx.x;
    const int tid = threadIdx.x;
    int k = counts[row];
    if (k > CAP) k = CAP;  // statistically impossible (max count ~60)
    const float Sv = S[tid];
    if (tid < k) {
        const int id = bucket[row * CAP + tid];
        eid_l[tid] = id;
        dst_l[tid] = ei[N_EDGES + id];
        e_l[tid] = e[id];
    }
    if (tid == 0) nw_s = 0;
    __syncthreads();

    // winner per (row,dst) cell = max edge id (last-write-wins scatter semantics)
    float mloc = 0.f;  // non-edge zeros always present -> m >= 0
    if (tid < k) {
        const int d = dst_l[tid];
        const int id = eid_l[tid];
        bool win = true;
        for (int s2 = 0; s2 < k; ++s2)
            if (dst_l[s2] == d && eid_l[s2] > id) { win = false; break; }
        if (win) {
            const float ev = e_l[tid];
            mloc = ev > 0.f ? ev : 0.f;
            const int p = atomicAdd(&nw_s, 1);
            cd[p] = d;
            cw[p] = ev;
        }
    }
    #pragma unroll
    for (int o = 32; o > 0; o >>= 1) mloc = fmaxf(mloc, __shfl_down(mloc, o));
    if ((tid & 63) == 0) redm[tid >> 6] = mloc;
    __syncthreads();
    const float m = fmaxf(redm[0], redm[1]);
    const int nw = nw_s;
    const float w0 = expf(-m);
    float sloc = 0.f;
    if (tid < nw) {
        const float w = expf(cw[tid] - m);
        sloc = w;
        cw[tid] = w - w0;
    }
    #pragma unroll
    for (int o = 32; o > 0; o >>= 1) sloc += __shfl_down(sloc, o);
    if ((tid & 63) == 0) reds[tid >> 6] = sloc;
    __syncthreads();  // also publishes cw updates
    const float D = (float)(N_NODES - nw) * w0 + reds[0] + reds[1];

    float acc = w0 * Sv;
    int j = 0;
    for (; j + 3 < nw; j += 4) {
        const float c0 = cw[j], c1 = cw[j+1], c2 = cw[j+2], c3 = cw[j+3];
        const int d0 = cd[j], d1 = cd[j+1], d2 = cd[j+2], d3 = cd[j+3];
        acc += c0 * h[(size_t)d0 * 128 + tid] + c1 * h[(size_t)d1 * 128 + tid]
             + c2 * h[(size_t)d2 * 128 + tid] + c3 * h[(size_t)d3 * 128 + tid];
    }
    for (; j < nw; ++j) acc += cw[j] * h[(size_t)cd[j] * 128 + tid];
    out[row * 128 + tid] = acc / D;
}

extern "C" void kernel_launch(void* const* d_in, const int* in_sizes, int n_in,
                              void* d_out, int out_size, void* d_ws, size_t ws_size,
                              hipStream_t stream) {
    const float* x = (const float*)d_in[0];
    const int* ei = (const int*)d_in[1];
    const float* ea = (const float*)d_in[2];
    const float* W = (const float*)d_in[3];
    const float* a = (const float*)d_in[4];
    float* out = (float*)d_out;

    char* ws = (char*)d_ws;
    float* h = (float*)(ws);                          // 4 MB
    int* bucket = (int*)(ws + (4 << 20));             // 4 MB
    float* e = (float*)(ws + (8 << 20));              // 1 MB
    float* asrc = (float*)(ws + (9 << 20));           // 32 KB
    float* adst = (float*)(ws + (9 << 20) + 32768);   // 32 KB
    int* counts = (int*)(ws + (9 << 20) + 65536);     // 32 KB
    float* S = (float*)(ws + (9 << 20) + 98304);      // 512 B (adjacent to counts)

    hipMemsetAsync(counts, 0, N_NODES * sizeof(int) + 128 * sizeof(float), stream);

    k_gemm<<<512, 256, 0, stream>>>(x, W, a, h, asrc, adst, S);
    k_edge<<<N_EDGES / 16, 256, 0, stream>>>(ei, ea, a, asrc, adst, e, counts, bucket);
    k_row<<<N_NODES, 128, 0, stream>>>(ei, e, counts, bucket, h, S, out);
}

// Round 4
// 79.708 us; speedup vs baseline: 1.6804x; 1.2377x over previous
//
#include <hip/hip_runtime.h>

#define N_NODES 8192
#define N_EDGES 262144
#define CAP 128
#define NB_GEMM 1024

// ---- K1: h = x@W^T (x tile in LDS, W rows from L2). Epilogue: asrc/adst shfl-dots,
//      per-block column-sum partials (NO atomics — they serialized at 4 cache lines).
__global__ __launch_bounds__(128) void k_gemm(const float* __restrict__ x,
                                              const float* __restrict__ W,
                                              const float* __restrict__ a,
                                              float* __restrict__ h,
                                              float* __restrict__ asrc,
                                              float* __restrict__ adst,
                                              float* __restrict__ Spart) {
    __shared__ float xs[8][128];
    __shared__ float ps[2][8], pd[2][8];
    const int col = threadIdx.x;
    const int r0 = blockIdx.x * 8;
    #pragma unroll
    for (int r = 0; r < 8; ++r) xs[r][col] = x[(size_t)(r0 + r) * 128 + col];
    __syncthreads();
    float acc[8] = {0.f,0.f,0.f,0.f,0.f,0.f,0.f,0.f};
    #pragma unroll 4
    for (int k0 = 0; k0 < 128; k0 += 4) {
        const float4 wv = *reinterpret_cast<const float4*>(&W[(size_t)col * 128 + k0]);
        #pragma unroll
        for (int r = 0; r < 8; ++r) {
            const float4 xv = *reinterpret_cast<const float4*>(&xs[r][k0]);
            acc[r] += xv.x*wv.x + xv.y*wv.y + xv.z*wv.z + xv.w*wv.w;
        }
    }
    float csum = 0.f;
    #pragma unroll
    for (int r = 0; r < 8; ++r) { h[(size_t)(r0 + r) * 128 + col] = acc[r]; csum += acc[r]; }
    Spart[(size_t)col * NB_GEMM + blockIdx.x] = csum;

    const float a1 = a[col], a2 = a[128 + col];
    const int wid = col >> 6;
    #pragma unroll
    for (int r = 0; r < 8; ++r) {
        float v1 = acc[r] * a1, v2 = acc[r] * a2;
        #pragma unroll
        for (int o = 32; o > 0; o >>= 1) { v1 += __shfl_down(v1, o); v2 += __shfl_down(v2, o); }
        if ((col & 63) == 0) { ps[wid][r] = v1; pd[wid][r] = v2; }
    }
    __syncthreads();
    if (col < 8)       asrc[r0 + col]     = ps[0][col]     + ps[1][col];
    else if (col < 16) adst[r0 + col - 8] = pd[0][col - 8] + pd[1][col - 8];
}

// ---- K1b: S[c] = deterministic tree-sum of 1024 per-block partials ----
__global__ __launch_bounds__(256) void k_sreduce(const float* __restrict__ Spart,
                                                 float* __restrict__ S) {
    __shared__ float red[256];
    const int c = blockIdx.x;
    const int tid = threadIdx.x;
    const float4 v = *reinterpret_cast<const float4*>(&Spart[(size_t)c * NB_GEMM + tid * 4]);
    red[tid] = v.x + v.y + v.z + v.w;
    __syncthreads();
    for (int o = 128; o > 0; o >>= 1) {
        if (tid < o) red[tid] += red[tid + o];
        __syncthreads();
    }
    if (tid == 0) S[c] = red[0];
}

// ---- K2: per-edge e = leakyrelu(asrc[s]+adst[t]+ea.a3); direct bucket scatter ----
__global__ __launch_bounds__(256) void k_edge(const int* __restrict__ ei,
                                              const float* __restrict__ ea,
                                              const float* __restrict__ a,
                                              const float* __restrict__ asrc,
                                              const float* __restrict__ adst,
                                              float* __restrict__ e,
                                              int* __restrict__ counts,
                                              int* __restrict__ bucket) {
    const int lane16 = threadIdx.x & 15;
    const int eid = blockIdx.x * 16 + (threadIdx.x >> 4);
    const float4 av = *reinterpret_cast<const float4*>(&a[256 + lane16 * 4]);
    const float4 ev = *reinterpret_cast<const float4*>(&ea[(size_t)eid * 64 + lane16 * 4]);
    float d = ev.x*av.x + ev.y*av.y + ev.z*av.z + ev.w*av.w;
    d += __shfl_xor(d, 1);
    d += __shfl_xor(d, 2);
    d += __shfl_xor(d, 4);
    d += __shfl_xor(d, 8);
    if (lane16 == 0) {
        const int s = ei[eid];
        const int t = ei[N_EDGES + eid];
        const float v = asrc[s] + adst[t] + d;
        e[eid] = v > 0.f ? v : 0.2f * v;
        const int pos = atomicAdd(&counts[s], 1);
        if (pos < CAP) bucket[s * CAP + pos] = eid;
    }
}

// ---- K3: per-row dedup (last-edge-wins) + sparse softmax + aggregate ----
// out_i = (w0*S + sum (exp(e-m)-w0)*h_dst) / D,  D=(N-nw)*w0 + sum exp(e-m)
__global__ __launch_bounds__(128) void k_row(const int* __restrict__ ei,
                                             const float* __restrict__ e,
                                             const int* __restrict__ counts,
                                             const int* __restrict__ bucket,
                                             const float* __restrict__ h,
                                             const float* __restrict__ S,
                                             float* __restrict__ out) {
    __shared__ int dst_l[CAP];
    __shared__ int eid_l[CAP];
    __shared__ float e_l[CAP];
    __shared__ float cw[CAP];
    __shared__ int cd[CAP];
    __shared__ float redm[2], reds[2];
    __shared__ int nw_s;

    const int row = blockIdx.x;
    const int tid = threadIdx.x;
    int k = counts[row];
    if (k > CAP) k = CAP;  // statistically impossible (max count ~60)
    const float Sv = S[tid];
    if (tid < k) {
        const int id = bucket[row * CAP + tid];
        eid_l[tid] = id;
        dst_l[tid] = ei[N_EDGES + id];
        e_l[tid] = e[id];
    }
    if (tid == 0) nw_s = 0;
    __syncthreads();

    // winner per (row,dst) cell = max edge id (last-write-wins scatter semantics)
    float mloc = 0.f;  // non-edge zeros always present -> m >= 0
    if (tid < k) {
        const int d = dst_l[tid];
        const int id = eid_l[tid];
        bool win = true;
        for (int s2 = 0; s2 < k; ++s2)
            if (dst_l[s2] == d && eid_l[s2] > id) { win = false; break; }
        if (win) {
            const float ev = e_l[tid];
            mloc = ev > 0.f ? ev : 0.f;
            const int p = atomicAdd(&nw_s, 1);
            cd[p] = d;
            cw[p] = ev;
        }
    }
    #pragma unroll
    for (int o = 32; o > 0; o >>= 1) mloc = fmaxf(mloc, __shfl_down(mloc, o));
    if ((tid & 63) == 0) redm[tid >> 6] = mloc;
    __syncthreads();
    const float m = fmaxf(redm[0], redm[1]);
    const int nw = nw_s;
    const float w0 = expf(-m);
    float sloc = 0.f;
    if (tid < nw) {
        const float w = expf(cw[tid] - m);
        sloc = w;
        cw[tid] = w - w0;
    }
    #pragma unroll
    for (int o = 32; o > 0; o >>= 1) sloc += __shfl_down(sloc, o);
    if ((tid & 63) == 0) reds[tid >> 6] = sloc;
    __syncthreads();  // also publishes cw updates
    const float D = (float)(N_NODES - nw) * w0 + reds[0] + reds[1];

    float acc = w0 * Sv;
    int j = 0;
    for (; j + 3 < nw; j += 4) {
        const float c0 = cw[j], c1 = cw[j+1], c2 = cw[j+2], c3 = cw[j+3];
        const int d0 = cd[j], d1 = cd[j+1], d2 = cd[j+2], d3 = cd[j+3];
        acc += c0 * h[(size_t)d0 * 128 + tid] + c1 * h[(size_t)d1 * 128 + tid]
             + c2 * h[(size_t)d2 * 128 + tid] + c3 * h[(size_t)d3 * 128 + tid];
    }
    for (; j < nw; ++j) acc += cw[j] * h[(size_t)cd[j] * 128 + tid];
    out[row * 128 + tid] = acc / D;
}

extern "C" void kernel_launch(void* const* d_in, const int* in_sizes, int n_in,
                              void* d_out, int out_size, void* d_ws, size_t ws_size,
                              hipStream_t stream) {
    const float* x = (const float*)d_in[0];
    const int* ei = (const int*)d_in[1];
    const float* ea = (const float*)d_in[2];
    const float* W = (const float*)d_in[3];
    const float* a = (const float*)d_in[4];
    float* out = (float*)d_out;

    char* ws = (char*)d_ws;
    float* h = (float*)(ws);                          // 4 MB
    int* bucket = (int*)(ws + (4 << 20));             // 4 MB
    float* e = (float*)(ws + (8 << 20));              // 1 MB
    float* Spart = (float*)(ws + (9 << 20));          // 512 KB
    float* asrc = (float*)(ws + (9 << 20) + 524288);  // 32 KB
    float* adst = (float*)(ws + (9 << 20) + 557056);  // 32 KB
    int* counts = (int*)(ws + (9 << 20) + 589824);    // 32 KB
    float* S = (float*)(ws + (9 << 20) + 622592);     // 512 B

    hipMemsetAsync(counts, 0, N_NODES * sizeof(int), stream);

    k_gemm<<<NB_GEMM, 128, 0, stream>>>(x, W, a, h, asrc, adst, Spart);
    k_sreduce<<<128, 256, 0, stream>>>(Spart, S);
    k_edge<<<N_EDGES / 16, 256, 0, stream>>>(ei, ea, a, asrc, adst, e, counts, bucket);
    k_row<<<N_NODES, 128, 0, stream>>>(ei, e, counts, bucket, h, S, out);
}

// Round 5
// 76.368 us; speedup vs baseline: 1.7539x; 1.0437x over previous
//
#include <hip/hip_runtime.h>

#define N_NODES 8192
#define N_EDGES 262144
#define CAP 128
#define BM 32
#define NB_GEMM 256   // N_NODES / BM

// ---- K1: h = x@W^T. Tiled SGEMM: x,W staged in LDS, 4x4 register tile/thread.
//      W stored XOR-swizzled so wv ds_read_b128 is bank-conflict-free.
//      Epilogue from registers: h store, column-sum partials, asrc/adst dots.
//      Also zeroes counts[] (replaces a memset dispatch).
__global__ __launch_bounds__(256) void k_gemm(const float* __restrict__ x,
                                              const float* __restrict__ W,
                                              const float* __restrict__ a,
                                              float* __restrict__ h,
                                              float* __restrict__ asrc,
                                              float* __restrict__ adst,
                                              float* __restrict__ Spart,
                                              int* __restrict__ counts) {
    __shared__ float wlds[128 * 128];   // 64 KB, swizzled columns
    __shared__ float xlds[BM * 128];    // 16 KB
    __shared__ float csum_l[8 * 132];   // per-tr column partials (padded)

    const int tid = threadIdx.x;
    const int tc = tid & 31;    // column tile: cols 4tc..4tc+3
    const int tr = tid >> 5;    // row tile: rows 4tr..4tr+3
    const int r0 = blockIdx.x * BM;

    if (tid < BM) counts[blockIdx.x * BM + tid] = 0;

    // stage x rows r0..r0+31 (1024 float4s, coalesced)
    #pragma unroll
    for (int i = tid; i < BM * 32; i += 256) {
        const int row = i >> 5, k4 = (i & 31) * 4;
        *reinterpret_cast<float4*>(&xlds[row * 128 + k4]) =
            *reinterpret_cast<const float4*>(&x[(size_t)(r0 + row) * 128 + k4]);
    }
    // stage W swizzled: word k of row wr lives at k ^ (((wr>>2)&7)<<2)
    #pragma unroll
    for (int i = tid; i < 4096; i += 256) {
        const int wr = i >> 5, k4 = (i & 31) * 4;
        const int ks = k4 ^ (((wr >> 2) & 7) << 2);
        *reinterpret_cast<float4*>(&wlds[wr * 128 + ks]) =
            *reinterpret_cast<const float4*>(&W[(size_t)wr * 128 + k4]);
    }
    __syncthreads();

    float acc[4][4];
    #pragma unroll
    for (int r = 0; r < 4; ++r)
        #pragma unroll
        for (int c = 0; c < 4; ++c) acc[r][c] = 0.f;

    #pragma unroll 8
    for (int k0 = 0; k0 < 128; k0 += 4) {
        float4 xv[4], wv[4];
        #pragma unroll
        for (int r = 0; r < 4; ++r)
            xv[r] = *reinterpret_cast<const float4*>(&xlds[(4 * tr + r) * 128 + k0]);
        #pragma unroll
        for (int c = 0; c < 4; ++c) {
            const int R = 4 * tc + c;
            wv[c] = *reinterpret_cast<const float4*>(&wlds[R * 128 + (k0 ^ (((R >> 2) & 7) << 2))]);
        }
        #pragma unroll
        for (int r = 0; r < 4; ++r)
            #pragma unroll
            for (int c = 0; c < 4; ++c)
                acc[r][c] += xv[r].x * wv[c].x + xv[r].y * wv[c].y
                           + xv[r].z * wv[c].z + xv[r].w * wv[c].w;
    }

    // h store (coalesced float4) + per-col partial sums
    #pragma unroll
    for (int r = 0; r < 4; ++r) {
        float4 o; o.x = acc[r][0]; o.y = acc[r][1]; o.z = acc[r][2]; o.w = acc[r][3];
        *reinterpret_cast<float4*>(&h[(size_t)(r0 + 4 * tr + r) * 128 + 4 * tc]) = o;
    }
    {
        float4 cs;
        cs.x = acc[0][0] + acc[1][0] + acc[2][0] + acc[3][0];
        cs.y = acc[0][1] + acc[1][1] + acc[2][1] + acc[3][1];
        cs.z = acc[0][2] + acc[1][2] + acc[2][2] + acc[3][2];
        cs.w = acc[0][3] + acc[1][3] + acc[2][3] + acc[3][3];
        *reinterpret_cast<float4*>(&csum_l[tr * 132 + 4 * tc]) = cs;
    }

    // asrc/adst: per-row dot with a over this thread's 4 cols, reduce across tc (32 lanes)
    const float4 a1 = *reinterpret_cast<const float4*>(&a[4 * tc]);
    const float4 a2 = *reinterpret_cast<const float4*>(&a[128 + 4 * tc]);
    #pragma unroll
    for (int r = 0; r < 4; ++r) {
        float v1 = acc[r][0]*a1.x + acc[r][1]*a1.y + acc[r][2]*a1.z + acc[r][3]*a1.w;
        float v2 = acc[r][0]*a2.x + acc[r][1]*a2.y + acc[r][2]*a2.z + acc[r][3]*a2.w;
        #pragma unroll
        for (int o = 16; o > 0; o >>= 1) { v1 += __shfl_down(v1, o); v2 += __shfl_down(v2, o); }
        if (tc == 0) {
            asrc[r0 + 4 * tr + r] = v1;
            adst[r0 + 4 * tr + r] = v2;
        }
    }
    __syncthreads();
    if (tid < 128) {
        float s = 0.f;
        #pragma unroll
        for (int t = 0; t < 8; ++t) s += csum_l[t * 132 + tid];
        Spart[(size_t)tid * NB_GEMM + blockIdx.x] = s;
    }
}

// ---- K1b: S[c] = tree-sum of 256 per-block partials (one wave per column) ----
__global__ __launch_bounds__(64) void k_sreduce(const float* __restrict__ Spart,
                                                float* __restrict__ S) {
    const int c = blockIdx.x, l = threadIdx.x;
    const float4 v = *reinterpret_cast<const float4*>(&Spart[(size_t)c * NB_GEMM + l * 4]);
    float s = v.x + v.y + v.z + v.w;
    #pragma unroll
    for (int o = 32; o > 0; o >>= 1) s += __shfl_down(s, o);
    if (l == 0) S[c] = s;
}

// ---- K2: per-edge e = leakyrelu(asrc[s]+adst[t]+ea.a3); direct bucket scatter ----
__global__ __launch_bounds__(256) void k_edge(const int* __restrict__ ei,
                                              const float* __restrict__ ea,
                                              const float* __restrict__ a,
                                              const float* __restrict__ asrc,
                                              const float* __restrict__ adst,
                                              float* __restrict__ e,
                                              int* __restrict__ counts,
                                              int* __restrict__ bucket) {
    const int lane16 = threadIdx.x & 15;
    const int eid = blockIdx.x * 16 + (threadIdx.x >> 4);
    const float4 av = *reinterpret_cast<const float4*>(&a[256 + lane16 * 4]);
    const float4 ev = *reinterpret_cast<const float4*>(&ea[(size_t)eid * 64 + lane16 * 4]);
    float d = ev.x*av.x + ev.y*av.y + ev.z*av.z + ev.w*av.w;
    d += __shfl_xor(d, 1);
    d += __shfl_xor(d, 2);
    d += __shfl_xor(d, 4);
    d += __shfl_xor(d, 8);
    if (lane16 == 0) {
        const int s = ei[eid];
        const int t = ei[N_EDGES + eid];
        const float v = asrc[s] + adst[t] + d;
        e[eid] = v > 0.f ? v : 0.2f * v;
        const int pos = atomicAdd(&counts[s], 1);
        if (pos < CAP) bucket[s * CAP + pos] = eid;
    }
}

// ---- K3: per-row dedup (last-edge-wins) + sparse softmax + aggregate ----
// out_i = (w0*S + sum (exp(e-m)-w0)*h_dst) / D,  D=(N-nw)*w0 + sum exp(e-m)
__global__ __launch_bounds__(128) void k_row(const int* __restrict__ ei,
                                             const float* __restrict__ e,
                                             const int* __restrict__ counts,
                                             const int* __restrict__ bucket,
                                             const float* __restrict__ h,
                                             const float* __restrict__ S,
                                             float* __restrict__ out) {
    __shared__ int dst_l[CAP];
    __shared__ int eid_l[CAP];
    __shared__ float e_l[CAP];
    __shared__ float cw[CAP];
    __shared__ int cd[CAP];
    __shared__ float redm[2], reds[2];
    __shared__ float4 xw[32];
    __shared__ int nw_s;

    const int row = blockIdx.x;
    const int tid = threadIdx.x;
    const int q = tid & 31;     // column quad: cols 4q..4q+3
    const int g = tid >> 5;     // dst subgroup 0..3
    int k = counts[row];
    if (k > CAP) k = CAP;  // statistically impossible (max count ~60)
    const float4 Sv4 = *reinterpret_cast<const float4*>(&S[4 * q]);
    if (tid < k) {
        const int id = bucket[row * CAP + tid];
        eid_l[tid] = id;
        dst_l[tid] = ei[N_EDGES + id];
        e_l[tid] = e[id];
    }
    if (tid == 0) nw_s = 0;
    __syncthreads();

    // winner per (row,dst) cell = max edge id (last-write-wins scatter semantics)
    float mloc = 0.f;  // non-edge zeros always present -> m >= 0
    if (tid < k) {
        const int d = dst_l[tid];
        const int id = eid_l[tid];
        bool win = true;
        for (int s2 = 0; s2 < k; ++s2)
            if (dst_l[s2] == d && eid_l[s2] > id) { win = false; break; }
        if (win) {
            const float ev = e_l[tid];
            mloc = ev > 0.f ? ev : 0.f;
            const int p = atomicAdd(&nw_s, 1);
            cd[p] = d;
            cw[p] = ev;
        }
    }
    #pragma unroll
    for (int o = 32; o > 0; o >>= 1) mloc = fmaxf(mloc, __shfl_down(mloc, o));
    if ((tid & 63) == 0) redm[tid >> 6] = mloc;
    __syncthreads();
    const float m = fmaxf(redm[0], redm[1]);
    const int nw = nw_s;
    const float w0 = expf(-m);
    float sloc = 0.f;
    if (tid < nw) {
        const float w = expf(cw[tid] - m);
        sloc = w;
        cw[tid] = w - w0;
    }
    #pragma unroll
    for (int o = 32; o > 0; o >>= 1) sloc += __shfl_down(sloc, o);
    if ((tid & 63) == 0) reds[tid >> 6] = sloc;
    __syncthreads();  // also publishes cw updates
    const float D = (float)(N_NODES - nw) * w0 + reds[0] + reds[1];

    // aggregate: 4 dst-groups in parallel, float4 per thread over column quad
    float4 acc4 = {0.f, 0.f, 0.f, 0.f};
    for (int j = g; j < nw; j += 4) {
        const float c_ = cw[j];
        const float4 hv = *reinterpret_cast<const float4*>(&h[(size_t)cd[j] * 128 + 4 * q]);
        acc4.x += c_ * hv.x;
        acc4.y += c_ * hv.y;
        acc4.z += c_ * hv.z;
        acc4.w += c_ * hv.w;
    }
    acc4.x += __shfl_down(acc4.x, 32);
    acc4.y += __shfl_down(acc4.y, 32);
    acc4.z += __shfl_down(acc4.z, 32);
    acc4.w += __shfl_down(acc4.w, 32);
    if (tid >= 64 && tid < 96) xw[q] = acc4;  // wave1 lanes 0-31 hold g2+g3
    __syncthreads();
    if (tid < 32) {
        const float4 t = xw[q];
        float4 o;
        o.x = (w0 * Sv4.x + acc4.x + t.x) / D;
        o.y = (w0 * Sv4.y + acc4.y + t.y) / D;
        o.z = (w0 * Sv4.z + acc4.z + t.z) / D;
        o.w = (w0 * Sv4.w + acc4.w + t.w) / D;
        *reinterpret_cast<float4*>(&out[(size_t)row * 128 + 4 * q]) = o;
    }
}

extern "C" void kernel_launch(void* const* d_in, const int* in_sizes, int n_in,
                              void* d_out, int out_size, void* d_ws, size_t ws_size,
                              hipStream_t stream) {
    const float* x = (const float*)d_in[0];
    const int* ei = (const int*)d_in[1];
    const float* ea = (const float*)d_in[2];
    const float* W = (const float*)d_in[3];
    const float* a = (const float*)d_in[4];
    float* out = (float*)d_out;

    char* ws = (char*)d_ws;
    float* h = (float*)(ws);                          // 4 MB
    int* bucket = (int*)(ws + (4 << 20));             // 4 MB
    float* e = (float*)(ws + (8 << 20));              // 1 MB
    float* Spart = (float*)(ws + (9 << 20));          // 128 KB
    float* asrc = (float*)(ws + (9 << 20) + 262144);  // 32 KB
    float* adst = (float*)(ws + (9 << 20) + 294912);  // 32 KB
    int* counts = (int*)(ws + (9 << 20) + 327680);    // 32 KB
    float* S = (float*)(ws + (9 << 20) + 360448);     // 512 B

    k_gemm<<<NB_GEMM, 256, 0, stream>>>(x, W, a, h, asrc, adst, Spart, counts);
    k_sreduce<<<128, 64, 0, stream>>>(Spart, S);
    k_edge<<<N_EDGES / 16, 256, 0, stream>>>(ei, ea, a, asrc, adst, e, counts, bucket);
    k_row<<<N_NODES, 128, 0, stream>>>(ei, e, counts, bucket, h, S, out);
}

// Round 6
// 74.245 us; speedup vs baseline: 1.8040x; 1.0286x over previous
//
#include <hip/hip_runtime.h>

#define N_NODES 8192
#define N_EDGES 262144
#define CAP 128
#define BM 16
#define NB_GEMM 512          // N_NODES / BM
#define NEB (N_EDGES / 16)   // edge blocks
#define NSB 32               // S-reduce blocks appended to k_edge

// ---- K1: h = x@W^T. Full W in LDS (XOR-swizzled, 2-way max = free), x tile in LDS.
//      256 thr = 64 tc (2 cols) x 4 tr (4 rows); grid 512 -> 2 blocks/CU, 2 waves/SIMD.
//      Epilogue: h, per-block column partials Spart, asrc/adst dots, zero counts.
__global__ __launch_bounds__(256) void k_gemm(const float* __restrict__ x,
                                              const float* __restrict__ W,
                                              const float* __restrict__ a,
                                              float* __restrict__ h,
                                              float* __restrict__ asrc,
                                              float* __restrict__ adst,
                                              float* __restrict__ Spart,
                                              int* __restrict__ counts) {
    __shared__ float wlds[128 * 128];   // 64 KB, swizzled: word k of row R at k^(((R>>1)&31)<<2)
    __shared__ float xlds[BM * 128];    // 8 KB
    __shared__ float csum_l[4 * 130];   // per-tr column partials

    const int tid = threadIdx.x;
    const int tc = tid & 63;            // cols 2tc, 2tc+1
    const int tr = tid >> 6;            // rows 4tr .. 4tr+3
    const int r0 = blockIdx.x * BM;

    if (tid < BM) counts[blockIdx.x * BM + tid] = 0;

    #pragma unroll
    for (int i = tid; i < BM * 32; i += 256) {
        const int row = i >> 5, k4 = (i & 31) << 2;
        *reinterpret_cast<float4*>(&xlds[row * 128 + k4]) =
            *reinterpret_cast<const float4*>(&x[(size_t)(r0 + row) * 128 + k4]);
    }
    #pragma unroll
    for (int i = tid; i < 4096; i += 256) {
        const int wr = i >> 5, k4 = (i & 31) << 2;
        const int ks = k4 ^ (((wr >> 1) & 31) << 2);
        *reinterpret_cast<float4*>(&wlds[wr * 128 + ks]) =
            *reinterpret_cast<const float4*>(&W[(size_t)wr * 128 + k4]);
    }
    __syncthreads();

    float acc[4][2] = {};
    const int R0 = 2 * tc;
    const int sw = (tc & 31) << 2;      // (R0>>1)&31 == (R1>>1)&31 == tc&31
    #pragma unroll 8
    for (int k0 = 0; k0 < 128; k0 += 4) {
        const int ks = k0 ^ sw;
        const float4 w0 = *reinterpret_cast<const float4*>(&wlds[R0 * 128 + ks]);
        const float4 w1 = *reinterpret_cast<const float4*>(&wlds[(R0 + 1) * 128 + ks]);
        #pragma unroll
        for (int r = 0; r < 4; ++r) {
            const float4 xv = *reinterpret_cast<const float4*>(&xlds[(4 * tr + r) * 128 + k0]);
            acc[r][0] += xv.x*w0.x + xv.y*w0.y + xv.z*w0.z + xv.w*w0.w;
            acc[r][1] += xv.x*w1.x + xv.y*w1.y + xv.z*w1.z + xv.w*w1.w;
        }
    }

    #pragma unroll
    for (int r = 0; r < 4; ++r) {
        float2 o; o.x = acc[r][0]; o.y = acc[r][1];
        *reinterpret_cast<float2*>(&h[(size_t)(r0 + 4 * tr + r) * 128 + 2 * tc]) = o;
    }
    {
        float2 cs;
        cs.x = acc[0][0] + acc[1][0] + acc[2][0] + acc[3][0];
        cs.y = acc[0][1] + acc[1][1] + acc[2][1] + acc[3][1];
        *reinterpret_cast<float2*>(&csum_l[tr * 130 + 2 * tc]) = cs;
    }

    const float a10 = a[2*tc], a11 = a[2*tc+1];
    const float a20 = a[128+2*tc], a21 = a[128+2*tc+1];
    #pragma unroll
    for (int r = 0; r < 4; ++r) {
        float v1 = acc[r][0]*a10 + acc[r][1]*a11;
        float v2 = acc[r][0]*a20 + acc[r][1]*a21;
        #pragma unroll
        for (int o = 32; o > 0; o >>= 1) { v1 += __shfl_down(v1, o); v2 += __shfl_down(v2, o); }
        if (tc == 0) { asrc[r0 + 4*tr + r] = v1; adst[r0 + 4*tr + r] = v2; }
    }
    __syncthreads();
    if (tid < 128) {
        const float s = csum_l[tid] + csum_l[130 + tid] + csum_l[260 + tid] + csum_l[390 + tid];
        Spart[(size_t)blockIdx.x * 128 + tid] = s;
    }
}

// ---- K2: per-edge e = leakyrelu(asrc[s]+adst[t]+ea.a3), bucket scatter.
//      Last NSB blocks instead reduce Spart -> S (k_edge never reads S; k_row does).
__global__ __launch_bounds__(256) void k_edge(const int* __restrict__ ei,
                                              const float* __restrict__ ea,
                                              const float* __restrict__ a,
                                              const float* __restrict__ asrc,
                                              const float* __restrict__ adst,
                                              float* __restrict__ e,
                                              int* __restrict__ counts,
                                              int* __restrict__ bucket,
                                              const float* __restrict__ Spart,
                                              float* __restrict__ S) {
    const int blk = blockIdx.x;
    if (blk >= NEB) {
        const int c = (blk - NEB) * 4 + (threadIdx.x >> 6);   // 128 waves -> 128 columns
        const int l = threadIdx.x & 63;
        float s = 0.f;
        #pragma unroll
        for (int j = 0; j < 8; ++j) s += Spart[(size_t)(l + 64 * j) * 128 + c];
        #pragma unroll
        for (int o = 32; o > 0; o >>= 1) s += __shfl_down(s, o);
        if (l == 0) S[c] = s;
        return;
    }
    const int lane16 = threadIdx.x & 15;
    const int eid = blk * 16 + (threadIdx.x >> 4);
    const float4 av = *reinterpret_cast<const float4*>(&a[256 + lane16 * 4]);
    const float4 ev = *reinterpret_cast<const float4*>(&ea[(size_t)eid * 64 + lane16 * 4]);
    float d = ev.x*av.x + ev.y*av.y + ev.z*av.z + ev.w*av.w;
    d += __shfl_xor(d, 1);
    d += __shfl_xor(d, 2);
    d += __shfl_xor(d, 4);
    d += __shfl_xor(d, 8);
    if (lane16 == 0) {
        const int s = ei[eid];
        const int t = ei[N_EDGES + eid];
        const float v = asrc[s] + adst[t] + d;
        e[eid] = v > 0.f ? v : 0.2f * v;
        const int pos = atomicAdd(&counts[s], 1);
        if (pos < CAP) bucket[s * CAP + pos] = eid;
    }
}

// ---- K3: per-row dedup (last-edge-wins) + sparse softmax + aggregate ----
// out_i = (w0*S + sum (exp(e-m)-w0)*h_dst) / D,  D=(N-nw)*w0 + sum exp(e-m)
__global__ __launch_bounds__(128) void k_row(const int* __restrict__ ei,
                                             const float* __restrict__ e,
                                             const int* __restrict__ counts,
                                             const int* __restrict__ bucket,
                                             const float* __restrict__ h,
                                             const float* __restrict__ S,
                                             float* __restrict__ out) {
    __shared__ int dst_l[CAP];
    __shared__ int eid_l[CAP];
    __shared__ float e_l[CAP];
    __shared__ float cw[CAP];
    __shared__ int cd[CAP];
    __shared__ float redm[2], reds[2];
    __shared__ float4 xw[32];
    __shared__ int nw_s;

    const int row = blockIdx.x;
    const int tid = threadIdx.x;
    const int q = tid & 31;     // column quad: cols 4q..4q+3
    const int g = tid >> 5;     // dst subgroup 0..3
    int k = counts[row];
    if (k > CAP) k = CAP;  // statistically impossible (max count ~60)
    const float4 Sv4 = *reinterpret_cast<const float4*>(&S[4 * q]);
    if (tid < k) {
        const int id = bucket[row * CAP + tid];
        eid_l[tid] = id;
        dst_l[tid] = ei[N_EDGES + id];
        e_l[tid] = e[id];
    }
    if (tid == 0) nw_s = 0;
    __syncthreads();

    // winner per (row,dst) cell = max edge id (last-write-wins scatter semantics)
    float mloc = 0.f;  // non-edge zeros always present -> m >= 0
    if (tid < k) {
        const int d = dst_l[tid];
        const int id = eid_l[tid];
        bool win = true;
        for (int s2 = 0; s2 < k; ++s2)
            if (dst_l[s2] == d && eid_l[s2] > id) { win = false; break; }
        if (win) {
            const float ev = e_l[tid];
            mloc = ev > 0.f ? ev : 0.f;
            const int p = atomicAdd(&nw_s, 1);
            cd[p] = d;
            cw[p] = ev;
        }
    }
    #pragma unroll
    for (int o = 32; o > 0; o >>= 1) mloc = fmaxf(mloc, __shfl_down(mloc, o));
    if ((tid & 63) == 0) redm[tid >> 6] = mloc;
    __syncthreads();
    const float m = fmaxf(redm[0], redm[1]);
    const int nw = nw_s;
    const float w0 = expf(-m);
    float sloc = 0.f;
    if (tid < nw) {
        const float w = expf(cw[tid] - m);
        sloc = w;
        cw[tid] = w - w0;
    }
    #pragma unroll
    for (int o = 32; o > 0; o >>= 1) sloc += __shfl_down(sloc, o);
    if ((tid & 63) == 0) reds[tid >> 6] = sloc;
    __syncthreads();  // also publishes cw updates
    const float D = (float)(N_NODES - nw) * w0 + reds[0] + reds[1];

    // aggregate: 4 dst-groups in parallel, float4 per thread over column quad
    float4 acc4 = {0.f, 0.f, 0.f, 0.f};
    for (int j = g; j < nw; j += 4) {
        const float c_ = cw[j];
        const float4 hv = *reinterpret_cast<const float4*>(&h[(size_t)cd[j] * 128 + 4 * q]);
        acc4.x += c_ * hv.x;
        acc4.y += c_ * hv.y;
        acc4.z += c_ * hv.z;
        acc4.w += c_ * hv.w;
    }
    acc4.x += __shfl_down(acc4.x, 32);
    acc4.y += __shfl_down(acc4.y, 32);
    acc4.z += __shfl_down(acc4.z, 32);
    acc4.w += __shfl_down(acc4.w, 32);
    if (tid >= 64 && tid < 96) xw[q] = acc4;  // wave1 lanes 0-31 hold g2+g3
    __syncthreads();
    if (tid < 32) {
        const float4 t = xw[q];
        float4 o;
        o.x = (w0 * Sv4.x + acc4.x + t.x) / D;
        o.y = (w0 * Sv4.y + acc4.y + t.y) / D;
        o.z = (w0 * Sv4.z + acc4.z + t.z) / D;
        o.w = (w0 * Sv4.w + acc4.w + t.w) / D;
        *reinterpret_cast<float4*>(&out[(size_t)row * 128 + 4 * q]) = o;
    }
}

extern "C" void kernel_launch(void* const* d_in, const int* in_sizes, int n_in,
                              void* d_out, int out_size, void* d_ws, size_t ws_size,
                              hipStream_t stream) {
    const float* x = (const float*)d_in[0];
    const int* ei = (const int*)d_in[1];
    const float* ea = (const float*)d_in[2];
    const float* W = (const float*)d_in[3];
    const float* a = (const float*)d_in[4];
    float* out = (float*)d_out;

    char* ws = (char*)d_ws;
    float* h = (float*)(ws);                          // 4 MB
    int* bucket = (int*)(ws + (4 << 20));             // 4 MB
    float* e = (float*)(ws + (8 << 20));              // 1 MB
    float* Spart = (float*)(ws + (9 << 20));          // 256 KB
    float* asrc = (float*)(ws + (9 << 20) + 262144);  // 32 KB
    float* adst = (float*)(ws + (9 << 20) + 294912);  // 32 KB
    int* counts = (int*)(ws + (9 << 20) + 327680);    // 32 KB
    float* S = (float*)(ws + (9 << 20) + 360448);     // 512 B

    k_gemm<<<NB_GEMM, 256, 0, stream>>>(x, W, a, h, asrc, adst, Spart, counts);
    k_edge<<<NEB + NSB, 256, 0, stream>>>(ei, ea, a, asrc, adst, e, counts, bucket, Spart, S);
    k_row<<<N_NODES, 128, 0, stream>>>(ei, e, counts, bucket, h, S, out);
}